// Round 10
// baseline (161.826 us; speedup 1.0000x reference)
//
#include <hip/hip_runtime.h>
#include <math.h>

// RansacRouting: B=32, I=1152, O=10, D=16, H=10, S=922
// Round 10: ONE WAVE PER TASK, single launch. Session model:
// dur_us = stream-chain + ~57us fixed (268MB re-poison fill; R5:147+57=204,
// R1:44+55, R9 4-launch chain ~50). R8 ablation: compute 19us = DPP
// reduction scaling with wave count (6w x 2244) + 2T tail of 6-wave blocks.
// Fix: 320 blocks x 64 thr, rpt=18 rows/thread (64x18=1152): reduction ops
// /task 6x down, no cross-wave combines, and two 1-wave blocks on a
// doubled-up CU run on DIFFERENT SIMDs -> no 2T serialization.
// Wave sums broadcast via readlane(63); Mu/loss/best computed redundantly
// on all lanes; lane0 stores the winning Mu. Contiguous rows per thread ->
// per-h mask test = one 2-word LDS read + 64-bit shift ([10][37], pad word).

#define B_    32
#define I_    1152
#define O_    10
#define D_    16
#define H_    10
#define S_    922
#define MASKW 37      // 36 words + 1 zero pad (safe unconditional 2-word read)
#define RPT   18      // rows per thread: 64*18 = 1152

// ---- wave64 sum via DPP (VALU pipe, no LDS) -- result valid in lane 63 ----
template <int CTRL, int ROWM>
static __device__ __forceinline__ float dpp_f(float v) {
    return __int_as_float(__builtin_amdgcn_update_dpp(
        0, __float_as_int(v), CTRL, ROWM, 0xf, true));
}
static __device__ __forceinline__ float wave_sum_f32(float v) {
    v += dpp_f<0x111, 0xf>(v);   // row_shr:1
    v += dpp_f<0x112, 0xf>(v);   // row_shr:2
    v += dpp_f<0x114, 0xf>(v);   // row_shr:4
    v += dpp_f<0x118, 0xf>(v);   // row_shr:8
    v += dpp_f<0x142, 0xa>(v);   // row_bcast15 -> rows 1,3
    v += dpp_f<0x143, 0xc>(v);   // row_bcast31 -> rows 2,3
    return v;                    // lane 63 holds the total
}
template <int CTRL, int ROWM>
static __device__ __forceinline__ double dpp_d(double v) {
    long long x = __double_as_longlong(v);
    int lo = (int)(unsigned)(x & 0xffffffffLL);
    int hi = (int)(x >> 32);
    lo = __builtin_amdgcn_update_dpp(0, lo, CTRL, ROWM, 0xf, true);
    hi = __builtin_amdgcn_update_dpp(0, hi, CTRL, ROWM, 0xf, true);
    return __longlong_as_double((long long)(unsigned)lo | ((long long)hi << 32));
}
static __device__ __forceinline__ double wave_sum_f64(double v) {
    v += dpp_d<0x111, 0xf>(v);
    v += dpp_d<0x112, 0xf>(v);
    v += dpp_d<0x114, 0xf>(v);
    v += dpp_d<0x118, 0xf>(v);
    v += dpp_d<0x142, 0xa>(v);
    v += dpp_d<0x143, 0xc>(v);
    return v;
}

// broadcast lane 63 -> all lanes
static __device__ __forceinline__ float bcast63_f(float v) {
    return __int_as_float(__builtin_amdgcn_readlane(__float_as_int(v), 63));
}
static __device__ __forceinline__ double bcast63_d(double v) {
    long long x = __double_as_longlong(v);
    int lo = __builtin_amdgcn_readlane((int)(unsigned)(x & 0xffffffffLL), 63);
    int hi = __builtin_amdgcn_readlane((int)(x >> 32), 63);
    return __longlong_as_double((long long)(unsigned)lo | ((long long)hi << 32));
}

// task index p -> (b, o): XCD-aware (b&7 == p&7)
static __device__ __forceinline__ void task_bo(int p, int& b, int& o) {
    int xcd = p & 7, g = p >> 3;
    int gg = g / O_;
    b = xcd + 8 * gg;
    o = g - O_ * gg;
}

__global__ __launch_bounds__(64, 1) void ransac_kernel(
    const float* __restrict__ up,      // [B,I,O,D]
    const int*   __restrict__ sidx,    // [B,S,O,H]
    float*       __restrict__ out)     // [B,O,D]
{
    __shared__ unsigned mask[H_][MASKW];    // 1480 B (incl. zero pad word)

    const int blk = blockIdx.x;
    int b, o; task_bo(blk, b, o);
    const int bo  = b * O_ + o;
    const int tid = threadIdx.x;            // 0..63 == lane

    // --- zero mask (incl. pad word) ---
    for (int t = tid; t < H_ * MASKW; t += 64) ((unsigned*)mask)[t] = 0u;
    __syncthreads();                        // 1 wave: just a waitcnt

    // --- scatter (consumed first; issue order == consumption order) ---
    const int* sb = sidx + (size_t)b * (S_ * O_ * H_) + o * H_;
    for (int s = tid; s < S_; s += 64) {
        const int2* ps = (const int2*)(sb + (size_t)s * (O_ * H_));
        int2 a0 = ps[0], a1 = ps[1], a2 = ps[2], a3 = ps[3], a4 = ps[4];
        int v[H_] = {a0.x, a0.y, a1.x, a1.y, a2.x, a2.y, a3.x, a3.y, a4.x, a4.y};
        #pragma unroll
        for (int h = 0; h < H_; ++h)
            atomicOr(&mask[h][v[h] >> 5], 1u << (v[h] & 31));
    }

    // --- u loads: own 18 CONTIGUOUS rows (tid*18 + r) ---
    const float* ub = up + ((size_t)b * I_ * O_ + o) * D_;
    float4 R[RPT][4];
    #pragma unroll
    for (int r = 0; r < RPT; ++r) {
        const float4* p = (const float4*)(ub + (size_t)(tid * RPT + r) * (O_ * D_));
        R[r][0] = p[0]; R[r][1] = p[1]; R[r][2] = p[2]; R[r][3] = p[3];
    }

    // --- vn per row ---
    float vn[RPT];
    #pragma unroll
    for (int r = 0; r < RPT; ++r) {
        float4 q0 = R[r][0], q1 = R[r][1], q2 = R[r][2], q3 = R[r][3];
        float s = q0.x*q0.x + q0.y*q0.y + q0.z*q0.z + q0.w*q0.w
                + q1.x*q1.x + q1.y*q1.y + q1.z*q1.z + q1.w*q1.w
                + q2.x*q2.x + q2.y*q2.y + q2.z*q2.z + q2.w*q2.w
                + q3.x*q3.x + q3.y*q3.y + q3.z*q3.z + q3.w*q3.w;
        vn[r] = sqrtf(s);
    }
    __syncthreads();   // mask complete (atomics drained)

    // --- tot pass (unmasked): tot[17] broadcast to all lanes ---
    float tot[17];
    {
        float na[17];
        #pragma unroll
        for (int d = 0; d < 17; ++d) na[d] = 0.f;
        #pragma unroll
        for (int r = 0; r < RPT; ++r) {
            float w = vn[r];
            float4 q0 = R[r][0], q1 = R[r][1], q2 = R[r][2], q3 = R[r][3];
            na[ 0] = fmaf(w, q0.x, na[ 0]); na[ 1] = fmaf(w, q0.y, na[ 1]);
            na[ 2] = fmaf(w, q0.z, na[ 2]); na[ 3] = fmaf(w, q0.w, na[ 3]);
            na[ 4] = fmaf(w, q1.x, na[ 4]); na[ 5] = fmaf(w, q1.y, na[ 5]);
            na[ 6] = fmaf(w, q1.z, na[ 6]); na[ 7] = fmaf(w, q1.w, na[ 7]);
            na[ 8] = fmaf(w, q2.x, na[ 8]); na[ 9] = fmaf(w, q2.y, na[ 9]);
            na[10] = fmaf(w, q2.z, na[10]); na[11] = fmaf(w, q2.w, na[11]);
            na[12] = fmaf(w, q3.x, na[12]); na[13] = fmaf(w, q3.y, na[13]);
            na[14] = fmaf(w, q3.z, na[14]); na[15] = fmaf(w, q3.w, na[15]);
            na[16] += w;
        }
        #pragma unroll
        for (int d = 0; d < 17; ++d) tot[d] = bcast63_f(wave_sum_f32(na[d]));
    }

    // --- usq per row (loss-phase invariant) ---
    float usq[RPT];
    #pragma unroll
    for (int r = 0; r < RPT; ++r) {
        float4 q0 = R[r][0], q1 = R[r][1], q2 = R[r][2], q3 = R[r][3];
        float uq[D_] = {q0.x,q0.y,q0.z,q0.w, q1.x,q1.y,q1.z,q1.w,
                        q2.x,q2.y,q2.z,q2.w, q3.x,q3.y,q3.z,q3.w};
        float t = 0.f;
        #pragma unroll
        for (int d = 0; d < D_; ++d) t = fmaf(uq[d], uq[d], t);
        usq[r] = t;
    }

    // --- per h: masked scan -> Mu -> loss -> running best ---
    const int bit0 = tid * RPT;            // first global row bit of this lane
    double bl = 0.0;
    float  mb[D_];
    #pragma unroll
    for (int d = 0; d < D_; ++d) mb[d] = 0.f;

    for (int h = 0; h < H_; ++h) {
        // 18 membership bits for rows [bit0, bit0+17]: one 2-word read
        unsigned lo = mask[h][bit0 >> 5];
        unsigned hi = mask[h][(bit0 >> 5) + 1];     // pad word safe
        unsigned mbits = (unsigned)(((((unsigned long long)hi) << 32) | lo)
                                    >> (bit0 & 31));

        float na[17];
        #pragma unroll
        for (int d = 0; d < 17; ++d) na[d] = 0.f;
        #pragma unroll
        for (int r = 0; r < RPT; ++r) {
            float w = (mbits & (1u << r)) ? 0.f : vn[r];   // sampled -> excluded
            float4 q0 = R[r][0], q1 = R[r][1], q2 = R[r][2], q3 = R[r][3];
            na[ 0] = fmaf(w, q0.x, na[ 0]); na[ 1] = fmaf(w, q0.y, na[ 1]);
            na[ 2] = fmaf(w, q0.z, na[ 2]); na[ 3] = fmaf(w, q0.w, na[ 3]);
            na[ 4] = fmaf(w, q1.x, na[ 4]); na[ 5] = fmaf(w, q1.y, na[ 5]);
            na[ 6] = fmaf(w, q1.z, na[ 6]); na[ 7] = fmaf(w, q1.w, na[ 7]);
            na[ 8] = fmaf(w, q2.x, na[ 8]); na[ 9] = fmaf(w, q2.y, na[ 9]);
            na[10] = fmaf(w, q2.z, na[10]); na[11] = fmaf(w, q2.w, na[11]);
            na[12] = fmaf(w, q3.x, na[12]); na[13] = fmaf(w, q3.y, na[13]);
            na[14] = fmaf(w, q3.z, na[14]); na[15] = fmaf(w, q3.w, na[15]);
            na[16] += w;
        }
        float sa[17];
        #pragma unroll
        for (int d = 0; d < 17; ++d) sa[d] = bcast63_f(wave_sum_f32(na[d]));

        // Mu (uniform across lanes)
        float rd = 1.f / (tot[16] - sa[16]);
        float mv[D_];
        #pragma unroll
        for (int d = 0; d < D_; ++d) mv[d] = (tot[d] - sa[d]) * rd;
        float musq = 0.f;
        #pragma unroll
        for (int d = 0; d < D_; ++d) musq = fmaf(mv[d], mv[d], musq);

        // loss over own 18 rows
        double l = 0.0;
        #pragma unroll
        for (int r = 0; r < RPT; ++r) {
            float4 q0 = R[r][0], q1 = R[r][1], q2 = R[r][2], q3 = R[r][3];
            float uq[D_] = {q0.x,q0.y,q0.z,q0.w, q1.x,q1.y,q1.z,q1.w,
                            q2.x,q2.y,q2.z,q2.w, q3.x,q3.y,q3.z,q3.w};
            float dot = 0.f;
            #pragma unroll
            for (int d = 0; d < D_; ++d) dot = fmaf(uq[d], mv[d], dot);
            float d2 = fmaf(-2.f, dot, usq[r] + musq);
            l += (double)sqrtf(fmaxf(d2, 0.f));
        }
        double ls = bcast63_d(wave_sum_f64(l));

        // running best (first-min tie-break == argmin)
        bool better = (h == 0) || (ls < bl);
        bl = better ? ls : bl;
        #pragma unroll
        for (int d = 0; d < D_; ++d) mb[d] = better ? mv[d] : mb[d];
    }

    if (tid == 0) {
        float* op = out + (size_t)bo * D_;
        *(float4*)(op +  0) = make_float4(mb[ 0], mb[ 1], mb[ 2], mb[ 3]);
        *(float4*)(op +  4) = make_float4(mb[ 4], mb[ 5], mb[ 6], mb[ 7]);
        *(float4*)(op +  8) = make_float4(mb[ 8], mb[ 9], mb[10], mb[11]);
        *(float4*)(op + 12) = make_float4(mb[12], mb[13], mb[14], mb[15]);
    }
}

extern "C" void kernel_launch(void* const* d_in, const int* in_sizes, int n_in,
                              void* d_out, int out_size, void* d_ws, size_t ws_size,
                              hipStream_t stream) {
    const float* up   = (const float*)d_in[0];
    const int*   sidx = (const int*)d_in[1];
    float*       out  = (float*)d_out;
    ransac_kernel<<<B_ * O_, 64, 0, stream>>>(up, sidx, out);
}